// Round 14
// baseline (1180.840 us; speedup 1.0000x reference)
//
#include <hip/hip_runtime.h>

// SoftMoe on MI355X (gfx950).
// R14: GEMM LDS halved to 64 KiB (single-buffer, rotating A-units) => 2
// blocks/CU. Six schedule variants at 128KiB/1-block all pinned at ~680 TF
// with NO resource >30% busy: stage(L2)+LDS-read+MFMA run ~serial because
// every barrier idles the whole CU. 2 blocks/CU lets one block's stall
// overlap the other's compute (m114). Rotation liveness (8-phase, BK=64):
//   B(T):     staged P1(T-1), read P0(T)     [B region dead after P0]
//   U0/U2(T): staged P2(T-1), read P0,P1(T)  [rows 0-63,128-191]
//   U1/U3(T): staged P0(T),   read P2,P3(T)  [rows 64-127,192-255]
// Gates: vmcnt(4) at P1 (protects P2 reads), vmcnt(0) at P3 (next tile's
// B+U0/U2 all needed at P0). Last tile: P1 gate vmcnt(0). Epilogues,
// swizzle (8-slot XOR), T1 XCD swizzle, and all non-GEMM kernels are
// byte-identical to R13.

#define DI __device__ __forceinline__

typedef __attribute__((ext_vector_type(8))) __bf16 bf16x8;
typedef __attribute__((ext_vector_type(8))) _Float16 f16x8;
typedef __attribute__((ext_vector_type(8))) short s16x8;
typedef __attribute__((ext_vector_type(4))) float f32x4;

DI short f2bf(float v) {
  union { float f; unsigned u; } a; a.f = v;
  unsigned u = a.u;
  unsigned r = (u + 0x7FFFu + ((u >> 16) & 1u)) >> 16;  // RNE
  return (short)r;
}
DI short f2h(float v) {
  union { _Float16 h[2]; short s[2]; } a;
  a.h[0] = (_Float16)v;  // RNE
  return a.s[0];
}

DI void gload_lds16(const void* g, void* l) {
  __builtin_amdgcn_global_load_lds(
      (__attribute__((address_space(1))) unsigned int*)g,
      (__attribute__((address_space(3))) unsigned int*)l, 16, 0, 0);
}

template <int EPI>
DI f32x4 mfop(s16x8 a, s16x8 b, f32x4 c) {
  if constexpr (EPI == 0)
    return __builtin_amdgcn_mfma_f32_16x16x32_f16(
        __builtin_bit_cast(f16x8, a), __builtin_bit_cast(f16x8, b), c, 0, 0, 0);
  else
    return __builtin_amdgcn_mfma_f32_16x16x32_bf16(
        __builtin_bit_cast(bf16x8, a), __builtin_bit_cast(bf16x8, b), c, 0, 0, 0);
}

// ---------------- conversion kernels ----------------

__global__ __launch_bounds__(256) void conv_x(const float* __restrict__ x,
                                              short* __restrict__ xh) {
  size_t i = ((size_t)blockIdx.x * 256 + threadIdx.x) * 8;
  float4 a = *(const float4*)(x + i);
  float4 b = *(const float4*)(x + i + 4);
  union { short s[8]; int4 q; } pk;
  pk.s[0] = f2h(a.x); pk.s[1] = f2h(a.y); pk.s[2] = f2h(a.z); pk.s[3] = f2h(a.w);
  pk.s[4] = f2h(b.x); pk.s[5] = f2h(b.y); pk.s[6] = f2h(b.z); pk.s[7] = f2h(b.w);
  *(int4*)(xh + i) = pk.q;
}

__global__ __launch_bounds__(256) void conv_phi(const float* __restrict__ phi,
                                                short* __restrict__ pT) {
  __shared__ short th[64][66];
  int dt = (blockIdx.x >> 6) * 64;
  int pt = (blockIdx.x & 63) * 64;
  int c = threadIdx.x & 63, r0 = threadIdx.x >> 6;
#pragma unroll
  for (int i = 0; i < 16; ++i) {
    int r = r0 + i * 4;
    th[r][c] = f2h(phi[(size_t)(dt + r) * 4096 + pt + c]);
  }
  __syncthreads();
#pragma unroll
  for (int i = 0; i < 16; ++i) {
    int u = r0 + i * 4;
    pT[(size_t)(pt + u) * 1024 + dt + c] = th[c][u];
  }
}

__global__ __launch_bounds__(256) void conv_w1(const float* __restrict__ W1,
                                               short* __restrict__ W1T) {
  __shared__ short t0[64][66];
  int n = blockIdx.y;
  int dt = (blockIdx.x >> 4) * 64;
  int ht = (blockIdx.x & 15) * 64;
  int c = threadIdx.x & 63, r0 = threadIdx.x >> 6;
  size_t base = (size_t)n << 20;
#pragma unroll
  for (int i = 0; i < 16; ++i) {
    int r = r0 + i * 4;
    t0[r][c] = f2bf(W1[base + (size_t)(dt + r) * 1024 + ht + c]);
  }
  __syncthreads();
#pragma unroll
  for (int i = 0; i < 16; ++i) {
    int u = r0 + i * 4;
    W1T[base + (size_t)(ht + u) * 1024 + dt + c] = t0[c][u];
  }
}

// ---- 8-phase GEMM: 256x256, BK=64, 8 waves, SINGLE 64KiB buffer ----
// K = 1024: NT = 16 tiles. 2 blocks/CU.

#define SGB() __builtin_amdgcn_sched_barrier(0)

#define MFQ(Q)                                                              \
  __builtin_amdgcn_s_setprio(1);                                            \
  _Pragma("unroll") for (int ks = 0; ks < 2; ++ks)                          \
  _Pragma("unroll") for (int r = 0; r < 2; ++r)                             \
  _Pragma("unroll") for (int j = 0; j < 4; ++j)                             \
      acc[2 * (Q) + r][j] =                                                 \
          mfop<EPI>(av[ks][r], bv[ks][j], acc[2 * (Q) + r][j]);             \
  __builtin_amdgcn_s_setprio(0)

// one phase: JIT reads -> stages+gate (__VA_ARGS__) -> barrier -> lgkm(0)
// -> MFMA -> barrier.  Gate in __VA_ARGS__ protects the NEXT phase's reads.
#define PHASE(Q, ...)                          \
  {                                            \
    if ((Q) == 0) reads_b();                   \
    reads_a(Q);                                \
    __VA_ARGS__;                               \
    if ((Q) == 0) asm volatile("s_waitcnt lgkmcnt(8)"); \
    SGB();                                     \
    __builtin_amdgcn_s_barrier();              \
    asm volatile("s_waitcnt lgkmcnt(0)");      \
    SGB();                                     \
    MFQ(Q);                                    \
    SGB();                                     \
    __builtin_amdgcn_s_barrier();              \
    SGB();                                     \
  }

template <int EPI>
__global__ __launch_bounds__(512, 4) void gemm_k(
    const short* __restrict__ A0, const short* __restrict__ B0,
    float* __restrict__ Cf, short* __restrict__ Cbs,
    const float* __restrict__ rowW, const float* __restrict__ colBias,
    float* __restrict__ G) {
  constexpr int TN = (EPI == 0) ? 16 : 4;
  constexpr size_t ASTR = (EPI == 0) ? (1u << 20) : (1u << 19);
  constexpr size_t BSTR = (EPI == 0) ? 0 : (1u << 20);
  constexpr int BMASK = (EPI == 2) ? 7 : 0xFFFF;

  __shared__ short lds[32768];  // A 32KB (4 units x 64 rows) + B 32KB = 64 KiB

  int y = blockIdx.y;
  // T1: XCD bijective swizzle (m204); gridX multiple of 8.
  int bx;
  {
    int q = gridDim.x >> 3;
    bx = (blockIdx.x & 7) * q + (blockIdx.x >> 3);
  }
  int brow = (bx / TN) * 256;
  int bcol = (bx % TN) * 256;
  int t = threadIdx.x, lane = t & 63, wid = t >> 6;
  int wm = wid >> 2, wn = wid & 3;  // 2 x 4 wave grid; per-wave C = 128 x 64
  int fr = lane & 15, fs = lane >> 4;

  const short* Abase = A0 + (size_t)y * ASTR + (size_t)brow * 1024;
  const short* Bbase = B0 + (size_t)(y & BMASK) * BSTR + (size_t)bcol * 1024;

  f32x4 acc[8][4] = {};

  // staging: one gload = 64 rows x 128B. Global source slot pre-swizzled by
  // the involution slot ^= row&7; LDS dest linear. Unit u = rows u*64..+63.
  size_t so0 = (size_t)(t >> 3) * 1024 + (size_t)(((t & 7) ^ ((t >> 3) & 7)) << 3);

  auto stageA = [&](int u, int tile) {
    gload_lds16(Abase + (size_t)u * 65536 + tile * 64 + so0,
                lds + u * 4096 + t * 8);
  };
  auto stageB = [&](int u, int tile) {
    gload_lds16(Bbase + (size_t)u * 65536 + tile * 64 + so0,
                lds + 16384 + u * 4096 + t * 8);
  };

  int ea0 = (fs ^ (fr & 7)) * 8;        // k-subtile 0 (swizzled slot)
  int ea1 = ((4 + fs) ^ (fr & 7)) * 8;  // k-subtile 1

  s16x8 av[2][2], bv[2][4];

  auto reads_b = [&]() {
    const short* base =
        lds + 16384 + (wn >> 1) * 8192 + ((wn & 1) * 64 + fr) * 64;
#pragma unroll
    for (int j = 0; j < 4; ++j) {
      bv[0][j] = *(const s16x8*)(base + j * 1024 + ea0);
      bv[1][j] = *(const s16x8*)(base + j * 1024 + ea1);
    }
  };
  auto reads_a = [&](int q) {
    const short* base = lds + wm * 8192 + (q * 32 + fr) * 64;
#pragma unroll
    for (int r = 0; r < 2; ++r) {
      av[0][r] = *(const s16x8*)(base + r * 1024 + ea0);
      av[1][r] = *(const s16x8*)(base + r * 1024 + ea1);
    }
  };

  // prologue: full tile 0 (A units 0-3, B units 0-3), drain, barrier.
  stageA(0, 0); stageA(1, 0); stageA(2, 0); stageA(3, 0);
  stageB(0, 0); stageB(1, 0); stageB(2, 0); stageB(3, 0);
  asm volatile("s_waitcnt vmcnt(0)");
  SGB();
  __builtin_amdgcn_s_barrier();
  SGB();

#pragma unroll 1
  for (int T = 0; T < 16; ++T) {
    // P0: read B(T)+A q0 (regions B, U0/U2); stage U1/U3(T) (dead since
    //     P3(T-1); for T=0 the prologue staged them).
    PHASE(0, if (T) { stageA(1, T); stageA(3, T); });
    // P1: read A q1 (U0/U2); stage B(T+1) (B dead after P0); gate vmcnt(4)
    //     -> U1/U3(T) landed before P2 reads (4 B-loads remain in flight).
    PHASE(1, if (T < 15) {
      stageB(0, T + 1); stageB(1, T + 1); stageB(2, T + 1); stageB(3, T + 1);
      asm volatile("s_waitcnt vmcnt(4)");
    } else {
      asm volatile("s_waitcnt vmcnt(0)");
    });
    // P2: read A q2 (U1/U3); stage U0/U2(T+1) (dead after P1).
    PHASE(2, if (T < 15) { stageA(0, T + 1); stageA(2, T + 1); });
    // P3: read A q3 (U1/U3); gate vmcnt(0) -> B(T+1)+U0/U2(T+1) landed
    //     before P0(T+1) reads.
    PHASE(3, if (T < 15) { asm volatile("s_waitcnt vmcnt(0)"); });
  }

  int fc = lane & 15, fq = (lane >> 4) * 4;

  if constexpr (EPI == 0) {
    short* LT = Cbs + ((size_t)y << 22);
#pragma unroll
    for (int i = 0; i < 8; ++i) {
      int r0 = brow + wm * 128 + i * 16 + fq;
#pragma unroll
      for (int j = 0; j < 4; ++j) {
        int c = bcol + wn * 64 + j * 16 + fc;
        union { short s[4]; int2 v2; } pk;
#pragma unroll
        for (int q = 0; q < 4; ++q) pk.s[q] = f2h(acc[i][j][q]);
        *(int2*)(LT + ((size_t)c << 10) + r0) = pk.v2;
      }
    }
    float* Pr = Cf + ((size_t)y << 17);  // [1024 m][64 chunks] float2
    int chunk = (bcol >> 6) + wn;
#pragma unroll
    for (int i = 0; i < 8; ++i) {
#pragma unroll
      for (int q = 0; q < 4; ++q) {
        float vm = fmaxf(fmaxf(acc[i][0][q], acc[i][1][q]),
                         fmaxf(acc[i][2][q], acc[i][3][q]));
#pragma unroll
        for (int d = 1; d < 16; d <<= 1) vm = fmaxf(vm, __shfl_xor(vm, d));
        float s = 0.f;
#pragma unroll
        for (int j = 0; j < 4; ++j) s += __expf(acc[i][j][q] - vm);
#pragma unroll
        for (int d = 1; d < 16; d <<= 1) s += __shfl_xor(s, d);
        if (fc == 0) {
          int m = brow + wm * 128 + i * 16 + fq + q;
          *(float2*)(Pr + ((size_t)m * 64 + chunk) * 2) = make_float2(vm, s);
        }
      }
    }
  } else {
    const float* cmv = rowW + ((size_t)y << 9);          // Cm slab (512 p-rows)
    const float* bb = colBias + ((size_t)(y & 7) << 10); // b1[n]
    float* g = G + ((size_t)y << 10);
#pragma unroll
    for (int j = 0; j < 4; ++j) {
      int c = bcol + wn * 64 + j * 16 + fc;  // h
      float bias = bb[c];
      float sum = 0.f;
#pragma unroll
      for (int i = 0; i < 8; ++i) {
        int r = brow + wm * 128 + i * 16 + fq;  // p
#pragma unroll
        for (int q = 0; q < 4; ++q) {
          float h = acc[i][j][q] + bias;
          h = fmaxf(h, 0.f);
          sum += cmv[r + q] * h;
        }
      }
      sum += __shfl_xor(sum, 16);
      sum += __shfl_xor(sum, 32);
      if (fq == 0) atomicAdd(&g[c], sum);
    }
  }
}

// ---------------- softmax stage ----------------

__global__ __launch_bounds__(256) void rowfin(const float* __restrict__ Pr,
                                              float* __restrict__ rowmax,
                                              float* __restrict__ rowinv,
                                              float* __restrict__ G) {
  if (blockIdx.x < 256) G[blockIdx.x * 256 + threadIdx.x] = 0.f;
  int row = blockIdx.x * 4 + (threadIdx.x >> 6);
  int lane = threadIdx.x & 63;
  float2 p = ((const float2*)Pr)[(size_t)row * 64 + lane];
  float vm = p.x;
#pragma unroll
  for (int d = 1; d < 64; d <<= 1) vm = fmaxf(vm, __shfl_xor(vm, d));
  float s = p.y * __expf(p.x - vm);
#pragma unroll
  for (int d = 1; d < 64; d <<= 1) s += __shfl_xor(s, d);
  if (lane == 0) {
    rowmax[row] = vm;
    rowinv[row] = 1.f / s;
  }
}

// per (b,np) row of LT: colmax, csum, Cm; threshold-compact significant
// (m, w) pairs via ballot prefix-sum into LDS; gather Xs = sum w*xh[m].
__global__ __launch_bounds__(256) void rowpass(const short* __restrict__ LT,
                                               const float* __restrict__ rowmax,
                                               const float* __restrict__ rowinv,
                                               const short* __restrict__ xh,
                                               short* __restrict__ Xs,
                                               float* __restrict__ Cm) {
  __shared__ int pm[4][32];
  __shared__ float pw[4][32];
  int id = blockIdx.x;  // 0..2047
  int b = id & 7;
  int np0 = (id >> 3) * 16;
  int wave = threadIdx.x >> 6, lane = threadIdx.x & 63;
  const float* rmax = rowmax + (b << 10);
  const float* rinv = rowinv + (b << 10);
  int m0 = lane * 16;
  unsigned long long ltmask = ((unsigned long long)1 << lane) - 1;
  float rm[16], ri[16];
#pragma unroll
  for (int i = 0; i < 4; ++i) {
    float4 a = ((const float4*)(rmax + m0))[i];
    rm[i * 4 + 0] = a.x; rm[i * 4 + 1] = a.y; rm[i * 4 + 2] = a.z; rm[i * 4 + 3] = a.w;
    float4 c = ((const float4*)(rinv + m0))[i];
    ri[i * 4 + 0] = c.x; ri[i * 4 + 1] = c.y; ri[i * 4 + 2] = c.z; ri[i * 4 + 3] = c.w;
  }
  const short* xb = xh + ((size_t)b << 20) + m0;
#pragma unroll
  for (int rr = wave; rr < 16; rr += 4) {
    int np = np0 + rr;
    size_t row = ((size_t)b << 12) + np;
    const f16x8* src = (const f16x8*)(LT + (row << 10) + m0);
    f16x8 h0 = src[0], h1 = src[1];
    float v[16];
#pragma unroll
    for (int k = 0; k < 8; ++k) { v[k] = (float)h0[k]; v[8 + k] = (float)h1[k]; }
    float vm = v[0];
#pragma unroll
    for (int k = 1; k < 16; ++k) vm = fmaxf(vm, v[k]);
#pragma unroll
    for (int d = 1; d < 64; d <<= 1) vm = fmaxf(vm, __shfl_xor(vm, d));
    float csum = 0.f, cms = 0.f;
#pragma unroll
    for (int k = 0; k < 16; ++k) {
      csum += __expf(v[k] - vm);
      cms += __expf(v[k] - rm[k]) * ri[k];
    }
#pragma unroll
    for (int d = 1; d < 64; d <<= 1) {
      csum += __shfl_xor(csum, d);
      cms += __shfl_xor(cms, d);
    }
    float inv = 1.f / csum;
    if (lane == 0) Cm[row] = cms * (1.f / 1024.f);
    float thr = vm - 18.f;
    int base = 0;
#pragma unroll
    for (int k = 0; k < 16; ++k) {
      bool sig = v[k] > thr;
      unsigned long long mk = __ballot(sig);
      if (sig) {
        int slot = base + __popcll(mk & ltmask);
        if (slot < 32) {
          pm[wave][slot] = m0 + k;
          pw[wave][slot] = __expf(v[k] - vm) * inv;
        }
      }
      base += __popcll(mk);
    }
    int n = base < 32 ? base : 32;
    asm volatile("s_waitcnt lgkmcnt(0)");
    float acc[16] = {};
    for (int i = 0; i < n; ++i) {
      int m = pm[wave][i];
      float w = pw[wave][i];
      const f16x8* xs = (const f16x8*)(xb + (size_t)m * 1024);
      f16x8 g0 = xs[0], g1 = xs[1];
#pragma unroll
      for (int j = 0; j < 8; ++j) {
        acc[j] += w * (float)g0[j];
        acc[8 + j] += w * (float)g1[j];
      }
    }
    union { short s[16]; int4 q[2]; } pk;
#pragma unroll
    for (int k = 0; k < 16; ++k) pk.s[k] = f2bf(acc[k]);
    int4* dst = (int4*)(Xs + (row << 10) + m0);
    dst[0] = pk.q[0];
    dst[1] = pk.q[1];
  }
}

// ---------------- final combine ----------------

__global__ __launch_bounds__(512) void yinit(const float* __restrict__ Cm,
                                             const float* __restrict__ b2,
                                             float* __restrict__ Y) {
  __shared__ float s[8];
  int b = blockIdx.x;
  int w = threadIdx.x >> 6, l = threadIdx.x & 63;
  float acc = 0.f;
  for (int p = l; p < 512; p += 64) acc += Cm[(b * 8 + w) * 512 + p];
  for (int d = 32; d; d >>= 1) acc += __shfl_xor(acc, d);
  if (l == 0) s[w] = acc;
  __syncthreads();
  int o = threadIdx.x;
  float yv = 0.f;
#pragma unroll
  for (int n = 0; n < 8; ++n) yv += s[n] * b2[n * 512 + o];
  Y[b * 512 + o] = yv;
}

__global__ __launch_bounds__(256) void gw2(const float* __restrict__ G,
                                           const float* __restrict__ W2,
                                           float* __restrict__ Y) {
  int o = blockIdx.x * 256 + threadIdx.x;
  int k0 = blockIdx.y * 256;
  float acc[8] = {};
  for (int kk = 0; kk < 256; ++kk) {
    int k = k0 + kk;
    float w = W2[(size_t)k * 512 + o];
#pragma unroll
    for (int b = 0; b < 8; ++b) acc[b] += G[b * 8192 + k] * w;
  }
#pragma unroll
  for (int b = 0; b < 8; ++b) atomicAdd(&Y[b * 512 + o], acc[b]);
}

// ---------------- launch ----------------

extern "C" void kernel_launch(void* const* d_in, const int* in_sizes, int n_in,
                              void* d_out, int out_size, void* d_ws, size_t ws_size,
                              hipStream_t stream) {
  const float* x = (const float*)d_in[0];
  const float* phi = (const float*)d_in[1];
  const float* W1 = (const float*)d_in[2];
  const float* b1 = (const float*)d_in[3];
  const float* W2 = (const float*)d_in[4];
  const float* b2 = (const float*)d_in[5];
  float* Y = (float*)d_out;

  size_t off = 0;
  auto alloc = [&](size_t n) {
    void* p = (char*)d_ws + off;
    off += (n + 255) & ~(size_t)255;
    return p;
  };
  short* LT = (short*)alloc(8ull * 4096 * 1024 * 2);   // 67.1 MB; Xs aliases
  short* Xs = LT;                                      // row-wise read->write
  short* xh = (short*)alloc(8ull * 1024 * 1024 * 2);   // fp16, live thru rowpass
  short* pT = (short*)alloc(4096ull * 1024 * 2);       // fp16, dead after gemm0
  short* W1T = (short*)alloc(8ull * 1024 * 1024 * 2);  // bf16, live thru gemm2
  float* Pr = (float*)alloc(8ull * 1024 * 64 * 2 * 4); // 4 MB partials
  float* rowmaxv = (float*)alloc(8192 * 4);
  float* rowinvv = (float*)alloc(8192 * 4);
  float* CmB = (float*)alloc(32768 * 4);
  float* G = (float*)alloc(8ull * 8192 * 4);
  // peak ~113 MiB

  conv_x<<<dim3(4096), 256, 0, stream>>>(x, xh);
  conv_phi<<<dim3(1024), 256, 0, stream>>>(phi, pT);
  conv_w1<<<dim3(256, 8), 256, 0, stream>>>(W1, W1T);

  // LT = (xh * pT)^T fp16 + Cw partials.  M=1024,N=4096 -> 4x16 tiles
  gemm_k<0><<<dim3(64, 8), 512, 0, stream>>>(xh, pT, Pr, LT,
                                             nullptr, nullptr, nullptr);
  rowfin<<<dim3(2048), 256, 0, stream>>>(Pr, rowmaxv, rowinvv, G);
  // threshold-compact + fused gather -> Xs (in-place over LT)
  rowpass<<<dim3(2048), 256, 0, stream>>>(LT, rowmaxv, rowinvv, xh, Xs, CmB);

  // G[b,n,h] = sum_p Cm * relu(Xs*W1T + b1).  M=512,N=1024 -> 2x4 tiles
  gemm_k<2><<<dim3(8, 64), 512, 0, stream>>>(Xs, W1T, nullptr, nullptr,
                                             CmB, b1, G);

  yinit<<<dim3(8), 512, 0, stream>>>(CmB, b2, Y);
  gw2<<<dim3(2, 32), 256, 0, stream>>>(G, W2, Y);
}

// Round 15
// 278.442 us; speedup vs baseline: 4.2409x; 4.2409x over previous
//
#include <hip/hip_runtime.h>

// SoftMoe on MI355X (gfx950).
// R15: R14's single-buffer 64KiB rotation kernel with the launch-bounds bug
// fixed: (512,4) forced VGPR<=128-class => compiler spilled acc[8][4] to
// scratch (VGPR=64, FETCH 1GB/dispatch, 540us). (512,2) restores natural
// ~116 VGPR; 64KiB LDS + VGPR<=128 => 2 blocks/CU (the isolated occupancy
// experiment R8/R14 both botched). Rotation schedule itself validated by
// R14's bit-identical absmax. All non-GEMM kernels byte-identical to R13.
//
// Rotation liveness (8-phase, BK=64, single buffer):
//   B(T):     staged P1(T-1), read P0(T)
//   U0/U2(T): staged P2(T-1), read P0,P1(T)
//   U1/U3(T): staged P0(T),   read P2,P3(T)
// Gates: vmcnt(4) at P1, vmcnt(0) at P3; last tile P1 gate vmcnt(0).

#define DI __device__ __forceinline__

typedef __attribute__((ext_vector_type(8))) __bf16 bf16x8;
typedef __attribute__((ext_vector_type(8))) _Float16 f16x8;
typedef __attribute__((ext_vector_type(8))) short s16x8;
typedef __attribute__((ext_vector_type(4))) float f32x4;

DI short f2bf(float v) {
  union { float f; unsigned u; } a; a.f = v;
  unsigned u = a.u;
  unsigned r = (u + 0x7FFFu + ((u >> 16) & 1u)) >> 16;  // RNE
  return (short)r;
}
DI short f2h(float v) {
  union { _Float16 h[2]; short s[2]; } a;
  a.h[0] = (_Float16)v;  // RNE
  return a.s[0];
}

DI void gload_lds16(const void* g, void* l) {
  __builtin_amdgcn_global_load_lds(
      (__attribute__((address_space(1))) unsigned int*)g,
      (__attribute__((address_space(3))) unsigned int*)l, 16, 0, 0);
}

template <int EPI>
DI f32x4 mfop(s16x8 a, s16x8 b, f32x4 c) {
  if constexpr (EPI == 0)
    return __builtin_amdgcn_mfma_f32_16x16x32_f16(
        __builtin_bit_cast(f16x8, a), __builtin_bit_cast(f16x8, b), c, 0, 0, 0);
  else
    return __builtin_amdgcn_mfma_f32_16x16x32_bf16(
        __builtin_bit_cast(bf16x8, a), __builtin_bit_cast(bf16x8, b), c, 0, 0, 0);
}

// ---------------- conversion kernels ----------------

__global__ __launch_bounds__(256) void conv_x(const float* __restrict__ x,
                                              short* __restrict__ xh) {
  size_t i = ((size_t)blockIdx.x * 256 + threadIdx.x) * 8;
  float4 a = *(const float4*)(x + i);
  float4 b = *(const float4*)(x + i + 4);
  union { short s[8]; int4 q; } pk;
  pk.s[0] = f2h(a.x); pk.s[1] = f2h(a.y); pk.s[2] = f2h(a.z); pk.s[3] = f2h(a.w);
  pk.s[4] = f2h(b.x); pk.s[5] = f2h(b.y); pk.s[6] = f2h(b.z); pk.s[7] = f2h(b.w);
  *(int4*)(xh + i) = pk.q;
}

__global__ __launch_bounds__(256) void conv_phi(const float* __restrict__ phi,
                                                short* __restrict__ pT) {
  __shared__ short th[64][66];
  int dt = (blockIdx.x >> 6) * 64;
  int pt = (blockIdx.x & 63) * 64;
  int c = threadIdx.x & 63, r0 = threadIdx.x >> 6;
#pragma unroll
  for (int i = 0; i < 16; ++i) {
    int r = r0 + i * 4;
    th[r][c] = f2h(phi[(size_t)(dt + r) * 4096 + pt + c]);
  }
  __syncthreads();
#pragma unroll
  for (int i = 0; i < 16; ++i) {
    int u = r0 + i * 4;
    pT[(size_t)(pt + u) * 1024 + dt + c] = th[c][u];
  }
}

__global__ __launch_bounds__(256) void conv_w1(const float* __restrict__ W1,
                                               short* __restrict__ W1T) {
  __shared__ short t0[64][66];
  int n = blockIdx.y;
  int dt = (blockIdx.x >> 4) * 64;
  int ht = (blockIdx.x & 15) * 64;
  int c = threadIdx.x & 63, r0 = threadIdx.x >> 6;
  size_t base = (size_t)n << 20;
#pragma unroll
  for (int i = 0; i < 16; ++i) {
    int r = r0 + i * 4;
    t0[r][c] = f2bf(W1[base + (size_t)(dt + r) * 1024 + ht + c]);
  }
  __syncthreads();
#pragma unroll
  for (int i = 0; i < 16; ++i) {
    int u = r0 + i * 4;
    W1T[base + (size_t)(ht + u) * 1024 + dt + c] = t0[c][u];
  }
}

// ---- 8-phase GEMM: 256x256, BK=64, 8 waves, SINGLE 64KiB buffer ----
// K = 1024: NT = 16 tiles. Target: 2 blocks/CU (VGPR<=128, LDS 64KiB).

#define SGB() __builtin_amdgcn_sched_barrier(0)

#define MFQ(Q)                                                              \
  __builtin_amdgcn_s_setprio(1);                                            \
  _Pragma("unroll") for (int ks = 0; ks < 2; ++ks)                          \
  _Pragma("unroll") for (int r = 0; r < 2; ++r)                             \
  _Pragma("unroll") for (int j = 0; j < 4; ++j)                             \
      acc[2 * (Q) + r][j] =                                                 \
          mfop<EPI>(av[ks][r], bv[ks][j], acc[2 * (Q) + r][j]);             \
  __builtin_amdgcn_s_setprio(0)

#define PHASE(Q, ...)                          \
  {                                            \
    if ((Q) == 0) reads_b();                   \
    reads_a(Q);                                \
    __VA_ARGS__;                               \
    if ((Q) == 0) asm volatile("s_waitcnt lgkmcnt(8)"); \
    SGB();                                     \
    __builtin_amdgcn_s_barrier();              \
    asm volatile("s_waitcnt lgkmcnt(0)");      \
    SGB();                                     \
    MFQ(Q);                                    \
    SGB();                                     \
    __builtin_amdgcn_s_barrier();              \
    SGB();                                     \
  }

template <int EPI>
__global__ __launch_bounds__(512, 2) void gemm_k(
    const short* __restrict__ A0, const short* __restrict__ B0,
    float* __restrict__ Cf, short* __restrict__ Cbs,
    const float* __restrict__ rowW, const float* __restrict__ colBias,
    float* __restrict__ G) {
  constexpr int TN = (EPI == 0) ? 16 : 4;
  constexpr size_t ASTR = (EPI == 0) ? (1u << 20) : (1u << 19);
  constexpr size_t BSTR = (EPI == 0) ? 0 : (1u << 20);
  constexpr int BMASK = (EPI == 2) ? 7 : 0xFFFF;

  __shared__ short lds[32768];  // A 32KB (4 units x 64 rows) + B 32KB = 64 KiB

  int y = blockIdx.y;
  // T1: XCD bijective swizzle (m204); gridX multiple of 8.
  int bx;
  {
    int q = gridDim.x >> 3;
    bx = (blockIdx.x & 7) * q + (blockIdx.x >> 3);
  }
  int brow = (bx / TN) * 256;
  int bcol = (bx % TN) * 256;
  int t = threadIdx.x, lane = t & 63, wid = t >> 6;
  int wm = wid >> 2, wn = wid & 3;  // 2 x 4 wave grid; per-wave C = 128 x 64
  int fr = lane & 15, fs = lane >> 4;

  const short* Abase = A0 + (size_t)y * ASTR + (size_t)brow * 1024;
  const short* Bbase = B0 + (size_t)(y & BMASK) * BSTR + (size_t)bcol * 1024;

  f32x4 acc[8][4] = {};

  // staging: one gload = 64 rows x 128B. Global source slot pre-swizzled by
  // the involution slot ^= row&7; LDS dest linear. Unit u = rows u*64..+63.
  size_t so0 = (size_t)(t >> 3) * 1024 + (size_t)(((t & 7) ^ ((t >> 3) & 7)) << 3);

  auto stageA = [&](int u, int tile) {
    gload_lds16(Abase + (size_t)u * 65536 + tile * 64 + so0,
                lds + u * 4096 + t * 8);
  };
  auto stageB = [&](int u, int tile) {
    gload_lds16(Bbase + (size_t)u * 65536 + tile * 64 + so0,
                lds + 16384 + u * 4096 + t * 8);
  };

  int ea0 = (fs ^ (fr & 7)) * 8;        // k-subtile 0 (swizzled slot)
  int ea1 = ((4 + fs) ^ (fr & 7)) * 8;  // k-subtile 1

  s16x8 av[2][2], bv[2][4];

  auto reads_b = [&]() {
    const short* base =
        lds + 16384 + (wn >> 1) * 8192 + ((wn & 1) * 64 + fr) * 64;
#pragma unroll
    for (int j = 0; j < 4; ++j) {
      bv[0][j] = *(const s16x8*)(base + j * 1024 + ea0);
      bv[1][j] = *(const s16x8*)(base + j * 1024 + ea1);
    }
  };
  auto reads_a = [&](int q) {
    const short* base = lds + wm * 8192 + (q * 32 + fr) * 64;
#pragma unroll
    for (int r = 0; r < 2; ++r) {
      av[0][r] = *(const s16x8*)(base + r * 1024 + ea0);
      av[1][r] = *(const s16x8*)(base + r * 1024 + ea1);
    }
  };

  // prologue: full tile 0 (A units 0-3, B units 0-3), drain, barrier.
  stageA(0, 0); stageA(1, 0); stageA(2, 0); stageA(3, 0);
  stageB(0, 0); stageB(1, 0); stageB(2, 0); stageB(3, 0);
  asm volatile("s_waitcnt vmcnt(0)");
  SGB();
  __builtin_amdgcn_s_barrier();
  SGB();

#pragma unroll 1
  for (int T = 0; T < 16; ++T) {
    // P0: read B(T)+A q0; stage U1/U3(T) (dead since P3(T-1); prologue for T=0).
    PHASE(0, if (T) { stageA(1, T); stageA(3, T); });
    // P1: read A q1; stage B(T+1) (B dead after P0); gate vmcnt(4) -> U1/U3
    //     landed before P2 reads (the 4 B-loads remain in flight).
    PHASE(1, if (T < 15) {
      stageB(0, T + 1); stageB(1, T + 1); stageB(2, T + 1); stageB(3, T + 1);
      asm volatile("s_waitcnt vmcnt(4)");
    } else {
      asm volatile("s_waitcnt vmcnt(0)");
    });
    // P2: read A q2; stage U0/U2(T+1) (dead after P1).
    PHASE(2, if (T < 15) { stageA(0, T + 1); stageA(2, T + 1); });
    // P3: read A q3; gate vmcnt(0) -> B(T+1)+U0/U2(T+1) landed before P0(T+1).
    PHASE(3, if (T < 15) { asm volatile("s_waitcnt vmcnt(0)"); });
  }

  int fc = lane & 15, fq = (lane >> 4) * 4;

  if constexpr (EPI == 0) {
    short* LT = Cbs + ((size_t)y << 22);
#pragma unroll
    for (int i = 0; i < 8; ++i) {
      int r0 = brow + wm * 128 + i * 16 + fq;
#pragma unroll
      for (int j = 0; j < 4; ++j) {
        int c = bcol + wn * 64 + j * 16 + fc;
        union { short s[4]; int2 v2; } pk;
#pragma unroll
        for (int q = 0; q < 4; ++q) pk.s[q] = f2h(acc[i][j][q]);
        *(int2*)(LT + ((size_t)c << 10) + r0) = pk.v2;
      }
    }
    float* Pr = Cf + ((size_t)y << 17);  // [1024 m][64 chunks] float2
    int chunk = (bcol >> 6) + wn;
#pragma unroll
    for (int i = 0; i < 8; ++i) {
#pragma unroll
      for (int q = 0; q < 4; ++q) {
        float vm = fmaxf(fmaxf(acc[i][0][q], acc[i][1][q]),
                         fmaxf(acc[i][2][q], acc[i][3][q]));
#pragma unroll
        for (int d = 1; d < 16; d <<= 1) vm = fmaxf(vm, __shfl_xor(vm, d));
        float s = 0.f;
#pragma unroll
        for (int j = 0; j < 4; ++j) s += __expf(acc[i][j][q] - vm);
#pragma unroll
        for (int d = 1; d < 16; d <<= 1) s += __shfl_xor(s, d);
        if (fc == 0) {
          int m = brow + wm * 128 + i * 16 + fq + q;
          *(float2*)(Pr + ((size_t)m * 64 + chunk) * 2) = make_float2(vm, s);
        }
      }
    }
  } else {
    const float* cmv = rowW + ((size_t)y << 9);          // Cm slab (512 p-rows)
    const float* bb = colBias + ((size_t)(y & 7) << 10); // b1[n]
    float* g = G + ((size_t)y << 10);
#pragma unroll
    for (int j = 0; j < 4; ++j) {
      int c = bcol + wn * 64 + j * 16 + fc;  // h
      float bias = bb[c];
      float sum = 0.f;
#pragma unroll
      for (int i = 0; i < 8; ++i) {
        int r = brow + wm * 128 + i * 16 + fq;  // p
#pragma unroll
        for (int q = 0; q < 4; ++q) {
          float h = acc[i][j][q] + bias;
          h = fmaxf(h, 0.f);
          sum += cmv[r + q] * h;
        }
      }
      sum += __shfl_xor(sum, 16);
      sum += __shfl_xor(sum, 32);
      if (fq == 0) atomicAdd(&g[c], sum);
    }
  }
}

// ---------------- softmax stage ----------------

__global__ __launch_bounds__(256) void rowfin(const float* __restrict__ Pr,
                                              float* __restrict__ rowmax,
                                              float* __restrict__ rowinv,
                                              float* __restrict__ G) {
  if (blockIdx.x < 256) G[blockIdx.x * 256 + threadIdx.x] = 0.f;
  int row = blockIdx.x * 4 + (threadIdx.x >> 6);
  int lane = threadIdx.x & 63;
  float2 p = ((const float2*)Pr)[(size_t)row * 64 + lane];
  float vm = p.x;
#pragma unroll
  for (int d = 1; d < 64; d <<= 1) vm = fmaxf(vm, __shfl_xor(vm, d));
  float s = p.y * __expf(p.x - vm);
#pragma unroll
  for (int d = 1; d < 64; d <<= 1) s += __shfl_xor(s, d);
  if (lane == 0) {
    rowmax[row] = vm;
    rowinv[row] = 1.f / s;
  }
}

// per (b,np) row of LT: colmax, csum, Cm; threshold-compact significant
// (m, w) pairs via ballot prefix-sum into LDS; gather Xs = sum w*xh[m].
__global__ __launch_bounds__(256) void rowpass(const short* __restrict__ LT,
                                               const float* __restrict__ rowmax,
                                               const float* __restrict__ rowinv,
                                               const short* __restrict__ xh,
                                               short* __restrict__ Xs,
                                               float* __restrict__ Cm) {
  __shared__ int pm[4][32];
  __shared__ float pw[4][32];
  int id = blockIdx.x;  // 0..2047
  int b = id & 7;
  int np0 = (id >> 3) * 16;
  int wave = threadIdx.x >> 6, lane = threadIdx.x & 63;
  const float* rmax = rowmax + (b << 10);
  const float* rinv = rowinv + (b << 10);
  int m0 = lane * 16;
  unsigned long long ltmask = ((unsigned long long)1 << lane) - 1;
  float rm[16], ri[16];
#pragma unroll
  for (int i = 0; i < 4; ++i) {
    float4 a = ((const float4*)(rmax + m0))[i];
    rm[i * 4 + 0] = a.x; rm[i * 4 + 1] = a.y; rm[i * 4 + 2] = a.z; rm[i * 4 + 3] = a.w;
    float4 c = ((const float4*)(rinv + m0))[i];
    ri[i * 4 + 0] = c.x; ri[i * 4 + 1] = c.y; ri[i * 4 + 2] = c.z; ri[i * 4 + 3] = c.w;
  }
  const short* xb = xh + ((size_t)b << 20) + m0;
#pragma unroll
  for (int rr = wave; rr < 16; rr += 4) {
    int np = np0 + rr;
    size_t row = ((size_t)b << 12) + np;
    const f16x8* src = (const f16x8*)(LT + (row << 10) + m0);
    f16x8 h0 = src[0], h1 = src[1];
    float v[16];
#pragma unroll
    for (int k = 0; k < 8; ++k) { v[k] = (float)h0[k]; v[8 + k] = (float)h1[k]; }
    float vm = v[0];
#pragma unroll
    for (int k = 1; k < 16; ++k) vm = fmaxf(vm, v[k]);
#pragma unroll
    for (int d = 1; d < 64; d <<= 1) vm = fmaxf(vm, __shfl_xor(vm, d));
    float csum = 0.f, cms = 0.f;
#pragma unroll
    for (int k = 0; k < 16; ++k) {
      csum += __expf(v[k] - vm);
      cms += __expf(v[k] - rm[k]) * ri[k];
    }
#pragma unroll
    for (int d = 1; d < 64; d <<= 1) {
      csum += __shfl_xor(csum, d);
      cms += __shfl_xor(cms, d);
    }
    float inv = 1.f / csum;
    if (lane == 0) Cm[row] = cms * (1.f / 1024.f);
    float thr = vm - 18.f;
    int base = 0;
#pragma unroll
    for (int k = 0; k < 16; ++k) {
      bool sig = v[k] > thr;
      unsigned long long mk = __ballot(sig);
      if (sig) {
        int slot = base + __popcll(mk & ltmask);
        if (slot < 32) {
          pm[wave][slot] = m0 + k;
          pw[wave][slot] = __expf(v[k] - vm) * inv;
        }
      }
      base += __popcll(mk);
    }
    int n = base < 32 ? base : 32;
    asm volatile("s_waitcnt lgkmcnt(0)");
    float acc[16] = {};
    for (int i = 0; i < n; ++i) {
      int m = pm[wave][i];
      float w = pw[wave][i];
      const f16x8* xs = (const f16x8*)(xb + (size_t)m * 1024);
      f16x8 g0 = xs[0], g1 = xs[1];
#pragma unroll
      for (int j = 0; j < 8; ++j) {
        acc[j] += w * (float)g0[j];
        acc[8 + j] += w * (float)g1[j];
      }
    }
    union { short s[16]; int4 q[2]; } pk;
#pragma unroll
    for (int k = 0; k < 16; ++k) pk.s[k] = f2bf(acc[k]);
    int4* dst = (int4*)(Xs + (row << 10) + m0);
    dst[0] = pk.q[0];
    dst[1] = pk.q[1];
  }
}

// ---------------- final combine ----------------

__global__ __launch_bounds__(512) void yinit(const float* __restrict__ Cm,
                                             const float* __restrict__ b2,
                                             float* __restrict__ Y) {
  __shared__ float s[8];
  int b = blockIdx.x;
  int w = threadIdx.x >> 6, l = threadIdx.x & 63;
  float acc = 0.f;
  for (int p = l; p < 512; p += 64) acc += Cm[(b * 8 + w) * 512 + p];
  for (int d = 32; d; d >>= 1) acc += __shfl_xor(acc, d);
  if (l == 0) s[w] = acc;
  __syncthreads();
  int o = threadIdx.x;
  float yv = 0.f;
#pragma unroll
  for (int n = 0; n < 8; ++n) yv += s[n] * b2[n * 512 + o];
  Y[b * 512 + o] = yv;
}

__global__ __launch_bounds__(256) void gw2(const float* __restrict__ G,
                                           const float* __restrict__ W2,
                                           float* __restrict__ Y) {
  int o = blockIdx.x * 256 + threadIdx.x;
  int k0 = blockIdx.y * 256;
  float acc[8] = {};
  for (int kk = 0; kk < 256; ++kk) {
    int k = k0 + kk;
    float w = W2[(size_t)k * 512 + o];
#pragma unroll
    for (int b = 0; b < 8; ++b) acc[b] += G[b * 8192 + k] * w;
  }
#pragma unroll
  for (int b = 0; b < 8; ++b) atomicAdd(&Y[b * 512 + o], acc[b]);
}

// ---------------- launch ----------------

extern "C" void kernel_launch(void* const* d_in, const int* in_sizes, int n_in,
                              void* d_out, int out_size, void* d_ws, size_t ws_size,
                              hipStream_t stream) {
  const float* x = (const float*)d_in[0];
  const float* phi = (const float*)d_in[1];
  const float* W1 = (const float*)d_in[2];
  const float* b1 = (const float*)d_in[3];
  const float* W2 = (const float*)d_in[4];
  const float* b2 = (const float*)d_in[5];
  float* Y = (float*)d_out;

  size_t off = 0;
  auto alloc = [&](size_t n) {
    void* p = (char*)d_ws + off;
    off += (n + 255) & ~(size_t)255;
    return p;
  };
  short* LT = (short*)alloc(8ull * 4096 * 1024 * 2);   // 67.1 MB; Xs aliases
  short* Xs = LT;                                      // row-wise read->write
  short* xh = (short*)alloc(8ull * 1024 * 1024 * 2);   // fp16, live thru rowpass
  short* pT = (short*)alloc(4096ull * 1024 * 2);       // fp16, dead after gemm0
  short* W1T = (short*)alloc(8ull * 1024 * 1024 * 2);  // bf16, live thru gemm2
  float* Pr = (float*)alloc(8ull * 1024 * 64 * 2 * 4); // 4 MB partials
  float* rowmaxv = (float*)alloc(8192 * 4);
  float* rowinvv = (float*)alloc(8192 * 4);
  float* CmB = (float*)alloc(32768 * 4);
  float* G = (float*)alloc(8ull * 8192 * 4);
  // peak ~113 MiB

  conv_x<<<dim3(4096), 256, 0, stream>>>(x, xh);
  conv_phi<<<dim3(1024), 256, 0, stream>>>(phi, pT);
  conv_w1<<<dim3(256, 8), 256, 0, stream>>>(W1, W1T);

  // LT = (xh * pT)^T fp16 + Cw partials.  M=1024,N=4096 -> 4x16 tiles
  gemm_k<0><<<dim3(64, 8), 512, 0, stream>>>(xh, pT, Pr, LT,
                                             nullptr, nullptr, nullptr);
  rowfin<<<dim3(2048), 256, 0, stream>>>(Pr, rowmaxv, rowinvv, G);
  // threshold-compact + fused gather -> Xs (in-place over LT)
  rowpass<<<dim3(2048), 256, 0, stream>>>(LT, rowmaxv, rowinvv, xh, Xs, CmB);

  // G[b,n,h] = sum_p Cm * relu(Xs*W1T + b1).  M=512,N=1024 -> 2x4 tiles
  gemm_k<2><<<dim3(8, 64), 512, 0, stream>>>(Xs, W1T, nullptr, nullptr,
                                             CmB, b1, G);

  yinit<<<dim3(8), 512, 0, stream>>>(CmB, b2, Y);
  gw2<<<dim3(2, 32), 256, 0, stream>>>(G, W2, Y);
}

// Round 16
// 243.771 us; speedup vs baseline: 4.8441x; 1.1422x over previous
//
#include <hip/hip_runtime.h>

// SoftMoe on MI355X (gfx950).
// R16 (consolidation): GEMM reverted to R13's double-buffered 8-phase
// (best measured: 99us; R15's single-buffer clean test refuted the
// occupancy hypothesis - LDS 64KiB + VGPR 104 left OccupancyPercent at 20%
// and time at 102us. 11 variants all ~680 TF => shape-bound at K=1024,
// above the m102 reference curve for this shape class). Tail trims:
//   * conv_x/conv_phi/conv_w1 fused into one flat-grid launch (-2 gaps)
//   * gw2 grid (2,32)->(2,128): 64 blocks left each CU pulling 262KB of
//     W2 at ~25GB/s/CU (~10us); 256 blocks cuts ~4x.
//
// Pipeline:
//   conv_all: x->xh fp16; phi->pT fp16 [np][d]; W1->W1T bf16 [n][h][d]
//   gemm<0>:  LT fp16 [b][np][m] = (xh*pT)^T + Cw row-softmax partials Pr
//   rowfin:   merge Pr -> rowmax/rowinv (+ zero G)
//   rowpass:  per (b,np) row: colmax, csum, Cm, threshold-compact -> gather Xs
//   gemm<2>:  relu(Xs*W1T+b1) contracted with Cm over p -> atomicAdd G
//   yinit + gw2: Y = G.W2 + (sum_p Cm).b2

#define DI __device__ __forceinline__

typedef __attribute__((ext_vector_type(8))) __bf16 bf16x8;
typedef __attribute__((ext_vector_type(8))) _Float16 f16x8;
typedef __attribute__((ext_vector_type(8))) short s16x8;
typedef __attribute__((ext_vector_type(4))) float f32x4;

DI short f2bf(float v) {
  union { float f; unsigned u; } a; a.f = v;
  unsigned u = a.u;
  unsigned r = (u + 0x7FFFu + ((u >> 16) & 1u)) >> 16;  // RNE
  return (short)r;
}
DI short f2h(float v) {
  union { _Float16 h[2]; short s[2]; } a;
  a.h[0] = (_Float16)v;  // RNE
  return a.s[0];
}

DI void gload_lds16(const void* g, void* l) {
  __builtin_amdgcn_global_load_lds(
      (__attribute__((address_space(1))) unsigned int*)g,
      (__attribute__((address_space(3))) unsigned int*)l, 16, 0, 0);
}

template <int EPI>
DI f32x4 mfop(s16x8 a, s16x8 b, f32x4 c) {
  if constexpr (EPI == 0)
    return __builtin_amdgcn_mfma_f32_16x16x32_f16(
        __builtin_bit_cast(f16x8, a), __builtin_bit_cast(f16x8, b), c, 0, 0, 0);
  else
    return __builtin_amdgcn_mfma_f32_16x16x32_bf16(
        __builtin_bit_cast(bf16x8, a), __builtin_bit_cast(bf16x8, b), c, 0, 0, 0);
}

// ---------------- fused conversion kernel ----------------
// flat grid 7168: [0,4096) x->xh elementwise; [4096,5120) phi->pT transpose;
// [5120,7168) W1->W1T transpose.

__global__ __launch_bounds__(256) void conv_all(const float* __restrict__ x,
                                                short* __restrict__ xh,
                                                const float* __restrict__ phi,
                                                short* __restrict__ pT,
                                                const float* __restrict__ W1,
                                                short* __restrict__ W1T) {
  __shared__ short t0[64][66];
  int id = blockIdx.x;
  int tid = threadIdx.x;
  if (id < 4096) {
    size_t i = ((size_t)id * 256 + tid) * 8;
    float4 a = *(const float4*)(x + i);
    float4 b = *(const float4*)(x + i + 4);
    union { short s[8]; int4 q; } pk;
    pk.s[0] = f2h(a.x); pk.s[1] = f2h(a.y); pk.s[2] = f2h(a.z); pk.s[3] = f2h(a.w);
    pk.s[4] = f2h(b.x); pk.s[5] = f2h(b.y); pk.s[6] = f2h(b.z); pk.s[7] = f2h(b.w);
    *(int4*)(xh + i) = pk.q;
    return;
  }
  int c = tid & 63, r0 = tid >> 6;
  if (id < 5120) {
    int bx = id - 4096;
    int dt = (bx >> 6) * 64;
    int pt = (bx & 63) * 64;
#pragma unroll
    for (int i = 0; i < 16; ++i) {
      int r = r0 + i * 4;
      t0[r][c] = f2h(phi[(size_t)(dt + r) * 4096 + pt + c]);
    }
    __syncthreads();
#pragma unroll
    for (int i = 0; i < 16; ++i) {
      int u = r0 + i * 4;
      pT[(size_t)(pt + u) * 1024 + dt + c] = t0[c][u];
    }
  } else {
    int bx = id - 5120;
    int n = bx >> 8;
    int xy = bx & 255;
    int dt = (xy >> 4) * 64;
    int ht = (xy & 15) * 64;
    size_t base = (size_t)n << 20;
#pragma unroll
    for (int i = 0; i < 16; ++i) {
      int r = r0 + i * 4;
      t0[r][c] = f2bf(W1[base + (size_t)(dt + r) * 1024 + ht + c]);
    }
    __syncthreads();
#pragma unroll
    for (int i = 0; i < 16; ++i) {
      int u = r0 + i * 4;
      W1T[base + (size_t)(ht + u) * 1024 + dt + c] = t0[c][u];
    }
  }
}

// ---- 8-phase GEMM: 256x256, BK=64, 8 waves, 2-buf, K=1024 (16 tiles) ----
// (R13 version: best measured, 99us, double-buffered 128KiB LDS)

#define SGB() __builtin_amdgcn_sched_barrier(0)

#define MFQ(Q)                                                              \
  __builtin_amdgcn_s_setprio(1);                                            \
  _Pragma("unroll") for (int ks = 0; ks < 2; ++ks)                          \
  _Pragma("unroll") for (int r = 0; r < 2; ++r)                             \
  _Pragma("unroll") for (int j = 0; j < 4; ++j)                             \
      acc[2 * (Q) + r][j] =                                                 \
          mfop<EPI>(av[ks][r], bv[ks][j], acc[2 * (Q) + r][j]);             \
  __builtin_amdgcn_s_setprio(0)

#define PHASE(D, Q, ...)                       \
  {                                            \
    if ((Q) == 0) reads_b(D);                  \
    reads_a(D, Q);                             \
    __VA_ARGS__;                               \
    if ((Q) == 0) asm volatile("s_waitcnt lgkmcnt(8)"); \
    SGB();                                     \
    __builtin_amdgcn_s_barrier();              \
    asm volatile("s_waitcnt lgkmcnt(0)");      \
    SGB();                                     \
    MFQ(Q);                                    \
    SGB();                                     \
    __builtin_amdgcn_s_barrier();              \
    SGB();                                     \
  }

template <int EPI>
__global__ __launch_bounds__(512, 2) void gemm_k(
    const short* __restrict__ A0, const short* __restrict__ B0,
    float* __restrict__ Cf, short* __restrict__ Cbs,
    const float* __restrict__ rowW, const float* __restrict__ colBias,
    float* __restrict__ G) {
  constexpr int TN = (EPI == 0) ? 16 : 4;
  constexpr size_t ASTR = (EPI == 0) ? (1u << 20) : (1u << 19);
  constexpr size_t BSTR = (EPI == 0) ? 0 : (1u << 20);
  constexpr int BMASK = (EPI == 2) ? 7 : 0xFFFF;

  __shared__ short lds[65536];  // 2 bufs x {A0,A1,B0,B1} x 16KB = 128 KiB

  int y = blockIdx.y;
  // T1: XCD bijective swizzle (m204); gridX multiple of 8.
  int bx;
  {
    int q = gridDim.x >> 3;
    bx = (blockIdx.x & 7) * q + (blockIdx.x >> 3);
  }
  int brow = (bx / TN) * 256;
  int bcol = (bx % TN) * 256;
  int t = threadIdx.x, lane = t & 63, wid = t >> 6;
  int wm = wid >> 2, wn = wid & 3;  // 2 x 4 wave grid; per-wave C = 128 x 64
  int fr = lane & 15, fs = lane >> 4;

  const short* Abase = A0 + (size_t)y * ASTR + (size_t)brow * 1024;
  const short* Bbase = B0 + (size_t)(y & BMASK) * BSTR + (size_t)bcol * 1024;

  f32x4 acc[8][4] = {};

  int li1 = 512 + t;
  size_t so0 = (size_t)(t >> 3) * 1024 + (size_t)(((t & 7) ^ ((t >> 3) & 7)) << 3);
  size_t so1 = (size_t)(li1 >> 3) * 1024 + (size_t)(((li1 & 7) ^ ((li1 >> 3) & 7)) << 3);

  auto stage = [&](bool isA, int half, int tile) {
    const short* gb = (isA ? Abase : Bbase) + (size_t)(half * 128) * 1024 + tile * 64;
    short* db = lds + (tile & 1) * 32768 + (isA ? 0 : 16384) + half * 8192 + t * 8;
    gload_lds16(gb + so0, db);
    gload_lds16(gb + so1, db + 4096);
  };

  int ea0 = (fs ^ (fr & 7)) * 8;
  int ea1 = ((4 + fs) ^ (fr & 7)) * 8;

  s16x8 av[2][2], bv[2][4];

  auto reads_b = [&](int d) {
    const short* base =
        lds + d * 32768 + 16384 + (wn >> 1) * 8192 + ((wn & 1) * 64 + fr) * 64;
#pragma unroll
    for (int j = 0; j < 4; ++j) {
      bv[0][j] = *(const s16x8*)(base + j * 1024 + ea0);
      bv[1][j] = *(const s16x8*)(base + j * 1024 + ea1);
    }
  };
  auto reads_a = [&](int d, int q) {
    const short* base = lds + d * 32768 + wm * 8192 + (q * 32 + fr) * 64;
#pragma unroll
    for (int r = 0; r < 2; ++r) {
      av[0][r] = *(const s16x8*)(base + r * 1024 + ea0);
      av[1][r] = *(const s16x8*)(base + r * 1024 + ea1);
    }
  };

  stage(false, 0, 0); stage(false, 1, 0);
  stage(true, 0, 0);  stage(true, 1, 0);
  stage(false, 0, 1); stage(false, 1, 1);
  asm volatile("s_waitcnt vmcnt(4)");
  SGB();
  __builtin_amdgcn_s_barrier();
  SGB();

#pragma unroll 1
  for (int i = 0; i < 7; ++i) {
    int t1 = 2 * i + 1, t2 = 2 * i + 2, t3 = 2 * i + 3;
    PHASE(0, 0, stage(true, 0, t1));
    PHASE(0, 1, stage(true, 1, t1); stage(false, 0, t2));
    PHASE(0, 2, stage(false, 1, t2));
    PHASE(0, 3, asm volatile("s_waitcnt vmcnt(4)"));
    PHASE(1, 0, stage(true, 0, t2));
    PHASE(1, 1, stage(true, 1, t2));
    PHASE(1, 2, stage(false, 0, t3));
    PHASE(1, 3, stage(false, 1, t3); asm volatile("s_waitcnt vmcnt(4)"));
  }
  PHASE(0, 0, stage(true, 0, 15));
  PHASE(0, 1, stage(true, 1, 15));
  PHASE(0, 2, );
  PHASE(0, 3, asm volatile("s_waitcnt vmcnt(0)"));
  PHASE(1, 0, );
  PHASE(1, 1, );
  PHASE(1, 2, );
  PHASE(1, 3, );

  int fc = lane & 15, fq = (lane >> 4) * 4;

  if constexpr (EPI == 0) {
    short* LT = Cbs + ((size_t)y << 22);
#pragma unroll
    for (int i = 0; i < 8; ++i) {
      int r0 = brow + wm * 128 + i * 16 + fq;
#pragma unroll
      for (int j = 0; j < 4; ++j) {
        int c = bcol + wn * 64 + j * 16 + fc;
        union { short s[4]; int2 v2; } pk;
#pragma unroll
        for (int q = 0; q < 4; ++q) pk.s[q] = f2h(acc[i][j][q]);
        *(int2*)(LT + ((size_t)c << 10) + r0) = pk.v2;
      }
    }
    float* Pr = Cf + ((size_t)y << 17);  // [1024 m][64 chunks] float2
    int chunk = (bcol >> 6) + wn;
#pragma unroll
    for (int i = 0; i < 8; ++i) {
#pragma unroll
      for (int q = 0; q < 4; ++q) {
        float vm = fmaxf(fmaxf(acc[i][0][q], acc[i][1][q]),
                         fmaxf(acc[i][2][q], acc[i][3][q]));
#pragma unroll
        for (int d = 1; d < 16; d <<= 1) vm = fmaxf(vm, __shfl_xor(vm, d));
        float s = 0.f;
#pragma unroll
        for (int j = 0; j < 4; ++j) s += __expf(acc[i][j][q] - vm);
#pragma unroll
        for (int d = 1; d < 16; d <<= 1) s += __shfl_xor(s, d);
        if (fc == 0) {
          int m = brow + wm * 128 + i * 16 + fq + q;
          *(float2*)(Pr + ((size_t)m * 64 + chunk) * 2) = make_float2(vm, s);
        }
      }
    }
  } else {
    const float* cmv = rowW + ((size_t)y << 9);          // Cm slab (512 p-rows)
    const float* bb = colBias + ((size_t)(y & 7) << 10); // b1[n]
    float* g = G + ((size_t)y << 10);
#pragma unroll
    for (int j = 0; j < 4; ++j) {
      int c = bcol + wn * 64 + j * 16 + fc;  // h
      float bias = bb[c];
      float sum = 0.f;
#pragma unroll
      for (int i = 0; i < 8; ++i) {
        int r = brow + wm * 128 + i * 16 + fq;  // p
#pragma unroll
        for (int q = 0; q < 4; ++q) {
          float h = acc[i][j][q] + bias;
          h = fmaxf(h, 0.f);
          sum += cmv[r + q] * h;
        }
      }
      sum += __shfl_xor(sum, 16);
      sum += __shfl_xor(sum, 32);
      if (fq == 0) atomicAdd(&g[c], sum);
    }
  }
}

// ---------------- softmax stage ----------------

__global__ __launch_bounds__(256) void rowfin(const float* __restrict__ Pr,
                                              float* __restrict__ rowmax,
                                              float* __restrict__ rowinv,
                                              float* __restrict__ G) {
  if (blockIdx.x < 256) G[blockIdx.x * 256 + threadIdx.x] = 0.f;
  int row = blockIdx.x * 4 + (threadIdx.x >> 6);
  int lane = threadIdx.x & 63;
  float2 p = ((const float2*)Pr)[(size_t)row * 64 + lane];
  float vm = p.x;
#pragma unroll
  for (int d = 1; d < 64; d <<= 1) vm = fmaxf(vm, __shfl_xor(vm, d));
  float s = p.y * __expf(p.x - vm);
#pragma unroll
  for (int d = 1; d < 64; d <<= 1) s += __shfl_xor(s, d);
  if (lane == 0) {
    rowmax[row] = vm;
    rowinv[row] = 1.f / s;
  }
}

// per (b,np) row of LT: colmax, csum, Cm; threshold-compact significant
// (m, w) pairs via ballot prefix-sum into LDS; gather Xs = sum w*xh[m].
__global__ __launch_bounds__(256) void rowpass(const short* __restrict__ LT,
                                               const float* __restrict__ rowmax,
                                               const float* __restrict__ rowinv,
                                               const short* __restrict__ xh,
                                               short* __restrict__ Xs,
                                               float* __restrict__ Cm) {
  __shared__ int pm[4][32];
  __shared__ float pw[4][32];
  int id = blockIdx.x;  // 0..2047
  int b = id & 7;
  int np0 = (id >> 3) * 16;
  int wave = threadIdx.x >> 6, lane = threadIdx.x & 63;
  const float* rmax = rowmax + (b << 10);
  const float* rinv = rowinv + (b << 10);
  int m0 = lane * 16;
  unsigned long long ltmask = ((unsigned long long)1 << lane) - 1;
  float rm[16], ri[16];
#pragma unroll
  for (int i = 0; i < 4; ++i) {
    float4 a = ((const float4*)(rmax + m0))[i];
    rm[i * 4 + 0] = a.x; rm[i * 4 + 1] = a.y; rm[i * 4 + 2] = a.z; rm[i * 4 + 3] = a.w;
    float4 c = ((const float4*)(rinv + m0))[i];
    ri[i * 4 + 0] = c.x; ri[i * 4 + 1] = c.y; ri[i * 4 + 2] = c.z; ri[i * 4 + 3] = c.w;
  }
  const short* xb = xh + ((size_t)b << 20) + m0;
#pragma unroll
  for (int rr = wave; rr < 16; rr += 4) {
    int np = np0 + rr;
    size_t row = ((size_t)b << 12) + np;
    const f16x8* src = (const f16x8*)(LT + (row << 10) + m0);
    f16x8 h0 = src[0], h1 = src[1];
    float v[16];
#pragma unroll
    for (int k = 0; k < 8; ++k) { v[k] = (float)h0[k]; v[8 + k] = (float)h1[k]; }
    float vm = v[0];
#pragma unroll
    for (int k = 1; k < 16; ++k) vm = fmaxf(vm, v[k]);
#pragma unroll
    for (int d = 1; d < 64; d <<= 1) vm = fmaxf(vm, __shfl_xor(vm, d));
    float csum = 0.f, cms = 0.f;
#pragma unroll
    for (int k = 0; k < 16; ++k) {
      csum += __expf(v[k] - vm);
      cms += __expf(v[k] - rm[k]) * ri[k];
    }
#pragma unroll
    for (int d = 1; d < 64; d <<= 1) {
      csum += __shfl_xor(csum, d);
      cms += __shfl_xor(cms, d);
    }
    float inv = 1.f / csum;
    if (lane == 0) Cm[row] = cms * (1.f / 1024.f);
    float thr = vm - 18.f;
    int base = 0;
#pragma unroll
    for (int k = 0; k < 16; ++k) {
      bool sig = v[k] > thr;
      unsigned long long mk = __ballot(sig);
      if (sig) {
        int slot = base + __popcll(mk & ltmask);
        if (slot < 32) {
          pm[wave][slot] = m0 + k;
          pw[wave][slot] = __expf(v[k] - vm) * inv;
        }
      }
      base += __popcll(mk);
    }
    int n = base < 32 ? base : 32;
    asm volatile("s_waitcnt lgkmcnt(0)");
    float acc[16] = {};
    for (int i = 0; i < n; ++i) {
      int m = pm[wave][i];
      float w = pw[wave][i];
      const f16x8* xs = (const f16x8*)(xb + (size_t)m * 1024);
      f16x8 g0 = xs[0], g1 = xs[1];
#pragma unroll
      for (int j = 0; j < 8; ++j) {
        acc[j] += w * (float)g0[j];
        acc[8 + j] += w * (float)g1[j];
      }
    }
    union { short s[16]; int4 q[2]; } pk;
#pragma unroll
    for (int k = 0; k < 16; ++k) pk.s[k] = f2bf(acc[k]);
    int4* dst = (int4*)(Xs + (row << 10) + m0);
    dst[0] = pk.q[0];
    dst[1] = pk.q[1];
  }
}

// ---------------- final combine ----------------

__global__ __launch_bounds__(512) void yinit(const float* __restrict__ Cm,
                                             const float* __restrict__ b2,
                                             float* __restrict__ Y) {
  __shared__ float s[8];
  int b = blockIdx.x;
  int w = threadIdx.x >> 6, l = threadIdx.x & 63;
  float acc = 0.f;
  for (int p = l; p < 512; p += 64) acc += Cm[(b * 8 + w) * 512 + p];
  for (int d = 32; d; d >>= 1) acc += __shfl_xor(acc, d);
  if (l == 0) s[w] = acc;
  __syncthreads();
  int o = threadIdx.x;
  float yv = 0.f;
#pragma unroll
  for (int n = 0; n < 8; ++n) yv += s[n] * b2[n * 512 + o];
  Y[b * 512 + o] = yv;
}

// grid (2,128): 64-k chunks so W2's 16.8MB is spread over 256 CUs
// (at (2,32), 64 blocks left each CU pulling 262KB at ~25GB/s/CU ~ 10us).
__global__ __launch_bounds__(256) void gw2(const float* __restrict__ G,
                                           const float* __restrict__ W2,
                                           float* __restrict__ Y) {
  int o = blockIdx.x * 256 + threadIdx.x;
  int k0 = blockIdx.y * 64;
  float acc[8] = {};
  for (int kk = 0; kk < 64; ++kk) {
    int k = k0 + kk;
    float w = W2[(size_t)k * 512 + o];
#pragma unroll
    for (int b = 0; b < 8; ++b) acc[b] += G[b * 8192 + k] * w;
  }
#pragma unroll
  for (int b = 0; b < 8; ++b) atomicAdd(&Y[b * 512 + o], acc[b]);
}

// ---------------- launch ----------------

extern "C" void kernel_launch(void* const* d_in, const int* in_sizes, int n_in,
                              void* d_out, int out_size, void* d_ws, size_t ws_size,
                              hipStream_t stream) {
  const float* x = (const float*)d_in[0];
  const float* phi = (const float*)d_in[1];
  const float* W1 = (const float*)d_in[2];
  const float* b1 = (const float*)d_in[3];
  const float* W2 = (const float*)d_in[4];
  const float* b2 = (const float*)d_in[5];
  float* Y = (float*)d_out;

  size_t off = 0;
  auto alloc = [&](size_t n) {
    void* p = (char*)d_ws + off;
    off += (n + 255) & ~(size_t)255;
    return p;
  };
  short* LT = (short*)alloc(8ull * 4096 * 1024 * 2);   // 67.1 MB; Xs aliases
  short* Xs = LT;                                      // row-wise read->write
  short* xh = (short*)alloc(8ull * 1024 * 1024 * 2);   // fp16, live thru rowpass
  short* pT = (short*)alloc(4096ull * 1024 * 2);       // fp16, dead after gemm0
  short* W1T = (short*)alloc(8ull * 1024 * 1024 * 2);  // bf16, live thru gemm2
  float* Pr = (float*)alloc(8ull * 1024 * 64 * 2 * 4); // 4 MB partials
  float* rowmaxv = (float*)alloc(8192 * 4);
  float* rowinvv = (float*)alloc(8192 * 4);
  float* CmB = (float*)alloc(32768 * 4);
  float* G = (float*)alloc(8ull * 8192 * 4);
  // peak ~113 MiB

  conv_all<<<dim3(7168), 256, 0, stream>>>(x, xh, phi, pT, W1, W1T);

  // LT = (xh * pT)^T fp16 + Cw partials.  M=1024,N=4096 -> 4x16 tiles
  gemm_k<0><<<dim3(64, 8), 512, 0, stream>>>(xh, pT, Pr, LT,
                                             nullptr, nullptr, nullptr);
  rowfin<<<dim3(2048), 256, 0, stream>>>(Pr, rowmaxv, rowinvv, G);
  // threshold-compact + fused gather -> Xs (in-place over LT)
  rowpass<<<dim3(2048), 256, 0, stream>>>(LT, rowmaxv, rowinvv, xh, Xs, CmB);

  // G[b,n,h] = sum_p Cm * relu(Xs*W1T + b1).  M=512,N=1024 -> 2x4 tiles
  gemm_k<2><<<dim3(8, 64), 512, 0, stream>>>(Xs, W1T, nullptr, nullptr,
                                             CmB, b1, G);

  yinit<<<dim3(8), 512, 0, stream>>>(CmB, b2, Y);
  gw2<<<dim3(2, 128), 256, 0, stream>>>(G, W2, Y);
}